// Round 5
// baseline (274.050 us; speedup 1.0000x reference)
//
#include <hip/hip_runtime.h>
#include <math.h>

// Round 13: delete whole passes.
//  - gemm_proj reads fp32 query/key/value DIRECTLY (reg-staged A: fp32
//    global_load_dwordx4 x2 -> cvt -> swizzled ds_write_b128, prefetched
//    during the compute phase; B side stays global_load_lds fp16 W).
//    Eliminates the q/k/v fp16 convert pass (18432 blocks, ~126MB traffic).
//  - RoPE fused into the projection epilogue: pairs (i, i+32) are the j and
//    j+2 fragments of the SAME lane.  512KB cos/sin table tab[p][i]
//    (generated in cvt's spare blocks, f64-reduced like the verified rope)
//    -> 2 coalesced float2 loads + 8 FMA per quad.  rope_qk kernel deleted;
//    rope now applies to fp32 acc BEFORE fp16 quantization.
//  - Launches 5 -> 4.
// gemm structure itself = round-12 (128^2/BK=64/4 waves, XCD-grouped decode,
// 0 bank conflicts).  attn_fused, gemm_out unchanged.
#define B_ 4
#define NQ 512
#define NK 2048
#define C_ 1024
#define H_ 16
#define D_ 64
#define KK 1024

typedef __attribute__((ext_vector_type(8))) _Float16 half8;
typedef __attribute__((ext_vector_type(4))) _Float16 half4;
typedef __attribute__((ext_vector_type(4))) float float4v;

// async global->LDS, 16B per lane (wave-uniform LDS base + lane*16 by HW)
__device__ __forceinline__ void g2l16(const _Float16* g, _Float16* l)
{
    __builtin_amdgcn_global_load_lds(
        (const __attribute__((address_space(1))) unsigned int*)g,
        (__attribute__((address_space(3))) unsigned int*)l, 16, 0, 0);
}

// ---------------------------------------------------------------------------
// W fp32->fp16 (blocks 0..4095) + rope table (blocks 4096..4351).
// tab[p*32+i] = (cos, sin) of p * 10000^(-i/32), p in [0,2048), i in [0,32).
// ---------------------------------------------------------------------------
__global__ __launch_bounds__(256) void cvt_w_tab(const float* __restrict__ W0,
                                                 const float* __restrict__ W1,
                                                 const float* __restrict__ W2,
                                                 const float* __restrict__ W3,
                                                 _Float16* __restrict__ W16,
                                                 float2* __restrict__ tab)
{
    const int blk = blockIdx.x;
    if (blk < 4096) {
        const int w = blk >> 10, row = blk & 1023;
        const float* src = (w == 0) ? W0 : (w == 1) ? W1 : (w == 2) ? W2 : W3;
        const int col = threadIdx.x * 4;
        float4 f = *(const float4*)(src + (size_t)row * 1024 + col);
        half4 h;
        h[0] = (_Float16)f.x; h[1] = (_Float16)f.y;
        h[2] = (_Float16)f.z; h[3] = (_Float16)f.w;
        *(half4*)(W16 + ((size_t)w << 20) + (size_t)row * 1024 + col) = h;
        return;
    }
    const int idx = (blk - 4096) * 256 + threadIdx.x;   // 0..65535
    const int p = idx >> 5, i = idx & 31;

    double f = 1.0;
    if (i & 1)  f *= 0.7498942093324559;    // 10^-0.125
    if (i & 2)  f *= 0.5623413251903491;    // 10^-0.25
    if (i & 4)  f *= 0.31622776601683794;   // 10^-0.5
    if (i & 8)  f *= 0.1;
    if (i & 16) f *= 0.01;

    const double ang = (double)p * f;
    const double TWO_PI = 6.2831853071795864769;
    const double INV_TWO_PI = 0.15915494309189533577;
    const float red = (float)(ang - TWO_PI * floor(ang * INV_TWO_PI));
    float s, c;
    sincosf(red, &s, &c);
    tab[idx] = make_float2(c, s);
}

// ---------------------------------------------------------------------------
// Projection GEMM: C[M][1024] = A_f32[M][1024] . W16[1024][1024]^T, fused
// fp32->fp16 A staging + RoPE epilogue (mode 0) / transposed scatter (mode 2).
// 128x128 tile, BK=64, 4 waves; XCD-grouped linear grid of 1152.
// LDS[row][c] = global[row][c ^ (row&7)] (chunk = 8 fp16); reads use the
// proven po = ((ks*4+quad)^(fm&7))*8 swizzle -> conflict-free.
// ---------------------------------------------------------------------------
__global__ __launch_bounds__(256) void gemm_proj(const float* __restrict__ qf,
                                                 const float* __restrict__ kf,
                                                 const float* __restrict__ vf,
                                                 const _Float16* __restrict__ W16,
                                                 const int* __restrict__ qpos,
                                                 const int* __restrict__ kpos,
                                                 const float2* __restrict__ tab,
                                                 _Float16* __restrict__ qhp,
                                                 _Float16* __restrict__ khp,
                                                 _Float16* __restrict__ vtp)
{
    __shared__ _Float16 sA[128 * 64];
    __shared__ _Float16 sB[128 * 64];

    const int lbid = blockIdx.x;            // 0..1151
    const int xcd = lbid & 7;
    const int seq = lbid >> 3;              // 0..143
    const int y = xcd + 8 * (seq >> 3);     // m-panel 0..143
    const int n0 = (seq & 7) * 128;

    const float* A; const _Float16* Bw; _Float16* Yh; const int* pos;
    int nsh, m0, mode; float scale;
    if (y < 64)       { A = kf; Bw = W16 + (1u << 20); Yh = khp; pos = kpos; nsh = 11; m0 = y * 128;         mode = 0; scale = 1.0f; }
    else if (y < 128) { A = vf; Bw = W16 + (2u << 20); Yh = vtp; pos = nullptr; nsh = 11; m0 = (y - 64) * 128;  mode = 2; scale = 0.0f; }
    else              { A = qf; Bw = W16;              Yh = qhp; pos = qpos; nsh = 9;  m0 = (y - 128) * 128; mode = 0; scale = 0.125f; }

    const int tid = threadIdx.x;
    const int lane = tid & 63, wave = tid >> 6;
    const int wm = (wave >> 1) * 64, wn = (wave & 1) * 64;
    const int fm = lane & 15, quad = lane >> 4;

    // staging lane geometry (rows are 8-aligned per wave-call, so row&7 == r0)
    const int r0 = lane >> 3;               // 0..7
    const int c4 = lane & 7;                // linear LDS chunk for A write
    const int sc = c4 ^ r0;                 // swizzled global chunk
    const float*    gAl = A  + (size_t)(m0 + wave * 32 + r0) * KK + sc * 8;
    const _Float16* gB  = Bw + (size_t)(n0 + wave * 32 + r0) * KK + sc * 8;

    float4v acc[4][4];
    #pragma unroll
    for (int i = 0; i < 4; ++i)
        #pragma unroll
        for (int j = 0; j < 4; ++j)
            #pragma unroll
            for (int e = 0; e < 4; ++e) acc[i][j][e] = 0.0f;

    float4 va[8];
    #pragma unroll
    for (int u = 0; u < 4; ++u) {
        va[2 * u]     = *(const float4*)(gAl + (size_t)u * 8 * KK);
        va[2 * u + 1] = *(const float4*)(gAl + (size_t)u * 8 * KK + 4);
    }

    for (int k0 = 0; k0 < KK; k0 += 64) {
        __syncthreads();                    // previous tile's readers done
        // stage: A regs -> LDS (swizzled), B async fp16
        #pragma unroll
        for (int u = 0; u < 4; ++u) {
            half8 h;
            h[0] = (_Float16)va[2 * u].x; h[1] = (_Float16)va[2 * u].y;
            h[2] = (_Float16)va[2 * u].z; h[3] = (_Float16)va[2 * u].w;
            h[4] = (_Float16)va[2 * u + 1].x; h[5] = (_Float16)va[2 * u + 1].y;
            h[6] = (_Float16)va[2 * u + 1].z; h[7] = (_Float16)va[2 * u + 1].w;
            *(half8*)&sA[(wave * 32 + u * 8 + r0) * 64 + c4 * 8] = h;
        }
        #pragma unroll
        for (int u = 0; u < 4; ++u)
            g2l16(gB + (size_t)u * 8 * KK + k0, &sB[(wave * 32 + u * 8) * 64]);
        __syncthreads();                    // tile visible (drains vm+lgkm)

        if (k0 + 64 < KK) {                 // prefetch next A during compute
            #pragma unroll
            for (int u = 0; u < 4; ++u) {
                va[2 * u]     = *(const float4*)(gAl + (size_t)u * 8 * KK + k0 + 64);
                va[2 * u + 1] = *(const float4*)(gAl + (size_t)u * 8 * KK + k0 + 68);
            }
        }

        #pragma unroll
        for (int ks = 0; ks < 2; ++ks) {
            const int po = ((ks * 4 + quad) ^ (fm & 7)) * 8;
            half8 a[4], b[4];
            #pragma unroll
            for (int i = 0; i < 4; ++i) {
                a[i] = *(const half8*)&sA[(wm + i * 16 + fm) * 64 + po];
                b[i] = *(const half8*)&sB[(wn + i * 16 + fm) * 64 + po];
            }
            __builtin_amdgcn_s_setprio(1);
            #pragma unroll
            for (int i = 0; i < 4; ++i)
                #pragma unroll
                for (int j = 0; j < 4; ++j)
                    acc[i][j] = __builtin_amdgcn_mfma_f32_16x16x32_f16(a[i], b[j], acc[i][j], 0, 0, 0);
            __builtin_amdgcn_s_setprio(0);
        }
    }

    const int rr = quad * 4;
    if (mode == 0) {
        // fused RoPE: within-head dim = j*16+fm; partners (i,i+32) = (j, j+2).
        const int nmask = (1 << nsh) - 1;
        const int hidx = (n0 + wn) >> 6;    // head, uniform per wave
        #pragma unroll
        for (int i = 0; i < 4; ++i)
            #pragma unroll
            for (int r = 0; r < 4; ++r) {
                const int m = m0 + wm + i * 16 + rr + r;
                const int b = m >> nsh, n = m & nmask;
                const int p = pos[(b << nsh) + n];
                const float2 cs0 = tab[p * 32 + fm];
                const float2 cs1 = tab[p * 32 + 16 + fm];
                const float x0 = acc[i][0][r], x2 = acc[i][2][r];
                const float x1 = acc[i][1][r], x3 = acc[i][3][r];
                const float o0 = (x0 * cs0.x - x2 * cs0.y) * scale;
                const float o2 = (x2 * cs0.x + x0 * cs0.y) * scale;
                const float o1 = (x1 * cs1.x - x3 * cs1.y) * scale;
                const float o3 = (x3 * cs1.x + x1 * cs1.y) * scale;
                const size_t base = ((((size_t)b * H_ + hidx) << nsh) + n) * 64 + fm;
                Yh[base +  0] = (_Float16)o0;
                Yh[base + 16] = (_Float16)o1;
                Yh[base + 32] = (_Float16)o2;
                Yh[base + 48] = (_Float16)o3;
            }
    } else {
        // V: transposed scatter [B,H,64,NK], no rope
        const int nmask = (1 << nsh) - 1;
        #pragma unroll
        for (int i = 0; i < 4; ++i)
            #pragma unroll
            for (int r = 0; r < 4; ++r) {
                const int m = m0 + wm + i * 16 + rr + r;
                const int b = m >> nsh, n = m & nmask;
                #pragma unroll
                for (int j = 0; j < 4; ++j) {
                    const int c = n0 + wn + j * 16 + fm;
                    Yh[(((size_t)(b * H_ + (c >> 6)) * 64) + (c & 63)) * NK + n] = (_Float16)acc[i][j][r];
                }
            }
    }
}

// ---------------------------------------------------------------------------
// Output projection (fp16 A via global_load_lds, fp32 out + bias).
// ---------------------------------------------------------------------------
__global__ __launch_bounds__(256) void gemm_out(const _Float16* __restrict__ A,
                                                const _Float16* __restrict__ Bw,
                                                float* __restrict__ Yf,
                                                const float* __restrict__ bias)
{
    __shared__ _Float16 sA[128 * 64];
    __shared__ _Float16 sB[128 * 64];

    const int tid = threadIdx.x;
    const int lane = tid & 63, wave = tid >> 6;
    const int n0 = blockIdx.x * 128, m0 = blockIdx.y * 128;
    const int wm = (wave >> 1) * 64, wn = (wave & 1) * 64;
    const int fm = lane & 15, quad = lane >> 4;

    const int srow = wave * 32 + (lane >> 3);
    const int soct = (lane & 7) ^ (srow & 7);
    const _Float16* gA = A  + (size_t)(m0 + srow) * KK + soct * 8;
    const _Float16* gB = Bw + (size_t)(n0 + srow) * KK + soct * 8;

    float4v acc[4][4];
    #pragma unroll
    for (int i = 0; i < 4; ++i)
        #pragma unroll
        for (int j = 0; j < 4; ++j)
            #pragma unroll
            for (int e = 0; e < 4; ++e) acc[i][j][e] = 0.0f;

    for (int k0 = 0; k0 < KK; k0 += 64) {
        __syncthreads();
        #pragma unroll
        for (int u = 0; u < 4; ++u) {
            g2l16(gA + (size_t)u * 8 * KK + k0, &sA[(wave * 32 + u * 8) * 64]);
            g2l16(gB + (size_t)u * 8 * KK + k0, &sB[(wave * 32 + u * 8) * 64]);
        }
        __syncthreads();

        #pragma unroll
        for (int ks = 0; ks < 2; ++ks) {
            const int po = ((ks * 4 + quad) ^ (fm & 7)) * 8;
            half8 a[4], b[4];
            #pragma unroll
            for (int i = 0; i < 4; ++i) {
                a[i] = *(const half8*)&sA[(wm + i * 16 + fm) * 64 + po];
                b[i] = *(const half8*)&sB[(wn + i * 16 + fm) * 64 + po];
            }
            __builtin_amdgcn_s_setprio(1);
            #pragma unroll
            for (int i = 0; i < 4; ++i)
                #pragma unroll
                for (int j = 0; j < 4; ++j)
                    acc[i][j] = __builtin_amdgcn_mfma_f32_16x16x32_f16(a[i], b[j], acc[i][j], 0, 0, 0);
            __builtin_amdgcn_s_setprio(0);
        }
    }

    const int rr = quad * 4;
    #pragma unroll
    for (int i = 0; i < 4; ++i)
        #pragma unroll
        for (int r = 0; r < 4; ++r) {
            const int m = m0 + wm + i * 16 + rr + r;
            #pragma unroll
            for (int j = 0; j < 4; ++j) {
                const int c = n0 + wn + j * 16 + fm;
                Yf[(size_t)m * 1024 + c] = acc[i][j][r] + bias[c];
            }
        }
}

// ---------------------------------------------------------------------------
// Fused flash attention (round 10, unchanged): LDS-shared K/V tiles,
// double-buffered global_load_lds staging, 8 waves each owning 16 queries.
// ---------------------------------------------------------------------------
__global__ __launch_bounds__(512) void attn_fused(const _Float16* __restrict__ qh,
                                                  const _Float16* __restrict__ kh,
                                                  const _Float16* __restrict__ vt,
                                                  _Float16* __restrict__ xw16)
{
    __shared__ _Float16 sK[2][64 * 64];
    __shared__ _Float16 sV[2][64 * 64];
    __shared__ _Float16 ps[8][16][66];

    const int tid = threadIdx.x;
    const int lane = tid & 63, wv = tid >> 6;   // 8 waves
    const int bhi = blockIdx.x & 63;            // XCD key
    const int qquad = blockIdx.x >> 6;          // 0..3
    const size_t bh = (size_t)bhi;
    const int qt = qquad * 8 + wv;              // q-tile 0..31 (16 queries)

    const int fm = lane & 15;
    const int quad = lane >> 4;
    const int fq = quad * 8;

    const _Float16* kb = kh + bh * NK * 64;
    const _Float16* vb = vt + bh * (size_t)64 * NK;

    const int r0 = lane >> 3;
    const int c4 = lane & 7;
    const int sch = c4 ^ r0;
    const _Float16* gK = kb + (size_t)(wv * 8 + r0) * 64 + sch * 8;
    const _Float16* gV = vb + (size_t)(wv * 8 + r0) * NK + sch * 8;

    const _Float16* qb = qh + (bh * NQ + (size_t)qt * 16) * 64;
    half8 aq[2];
    aq[0] = *(const half8*)(qb + (size_t)fm * 64 + fq);
    aq[1] = *(const half8*)(qb + (size_t)fm * 64 + 32 + fq);

    float l_acc[4] = {};
    float4v O[4];
    #pragma unroll
    for (int j = 0; j < 4; ++j)
        #pragma unroll
        for (int e = 0; e < 4; ++e) O[j][e] = 0.0f;

    const float4v z4 = {0.0f, 0.0f, 0.0f, 0.0f};

    g2l16(gK, &sK[0][wv * 512]);
    g2l16(gV, &sV[0][wv * 512]);
    __syncthreads();

    for (int it = 0; it < 32; ++it) {
        const int cur = it & 1;
        if (it < 31) {
            g2l16(gK + (size_t)(it + 1) * 64 * 64, &sK[cur ^ 1][wv * 512]);
            g2l16(gV + (it + 1) * 64,              &sV[cur ^ 1][wv * 512]);
        }
        const _Float16* Kc = sK[cur];
        const _Float16* Vc = sV[cur];

        half8 bk[4][2];
        #pragma unroll
        for (int j = 0; j < 4; ++j)
            #pragma unroll
            for (int ks = 0; ks < 2; ++ks)
                bk[j][ks] = *(const half8*)&Kc[(j * 16 + fm) * 64 + (((ks * 4 + quad) ^ (fm & 7)) * 8)];

        float4v s[4];
        __builtin_amdgcn_s_setprio(1);
        #pragma unroll
        for (int j = 0; j < 4; ++j) {
            s[j] = __builtin_amdgcn_mfma_f32_16x16x32_f16(aq[0], bk[j][0], z4, 0, 0, 0);
            s[j] = __builtin_amdgcn_mfma_f32_16x16x32_f16(aq[1], bk[j][1], s[j], 0, 0, 0);
        }
        __builtin_amdgcn_s_setprio(0);

        half8 bv[4][2];
        #pragma unroll
        for (int j = 0; j < 4; ++j)
            #pragma unroll
            for (int ks = 0; ks < 2; ++ks)
                bv[j][ks] = *(const half8*)&Vc[(j * 16 + fm) * 64 + (((ks * 4 + quad) ^ (fm & 7)) * 8)];

        #pragma unroll
        for (int j = 0; j < 4; ++j)
            #pragma unroll
            for (int r = 0; r < 4; ++r) {
                const float p = __expf(s[j][r]);
                l_acc[r] += p;
                ps[wv][quad * 4 + r][16 * j + fm] = (_Float16)p;
            }

        __builtin_amdgcn_s_setprio(1);
        #pragma unroll
        for (int ks = 0; ks < 2; ++ks) {
            half8 pa = *(const half8*)&ps[wv][fm][ks * 32 + fq];
            #pragma unroll
            for (int j = 0; j < 4; ++j)
                O[j] = __builtin_amdgcn_mfma_f32_16x16x32_f16(pa, bv[j][ks], O[j], 0, 0, 0);
        }
        __builtin_amdgcn_s_setprio(0);

        __syncthreads();
    }

    #pragma unroll
    for (int r = 0; r < 4; ++r) {
        float l = l_acc[r];
        l += __shfl_xor(l, 1);
        l += __shfl_xor(l, 2);
        l += __shfl_xor(l, 4);
        l += __shfl_xor(l, 8);
        const float inv = 1.0f / l;
        const int qr = quad * 4 + r;
        const int row = (bhi >> 4) * 512 + qt * 16 + qr;
        #pragma unroll
        for (int j = 0; j < 4; ++j) {
            const int col = (bhi & 15) * 64 + j * 16 + fm;
            xw16[(size_t)row * 1024 + col] = (_Float16)(O[j][r] * inv);
        }
    }
}

// ---------------------------------------------------------------------------
extern "C" void kernel_launch(void* const* d_in, const int* in_sizes, int n_in,
                              void* d_out, int out_size, void* d_ws, size_t ws_size,
                              hipStream_t stream)
{
    const float* query = (const float*)d_in[0];
    const float* key   = (const float*)d_in[1];
    const float* value = (const float*)d_in[2];
    const int*   qpos  = (const int*)d_in[3];
    const int*   kpos  = (const int*)d_in[4];
    const float* Wq    = (const float*)d_in[5];
    const float* Wk    = (const float*)d_in[6];
    const float* Wv    = (const float*)d_in[7];
    const float* Wp    = (const float*)d_in[8];
    const float* bp    = (const float*)d_in[9];
    float* out = (float*)d_out;

    // ws layout (MiB), 80 total:
    //  0..1  : tab [2048][32] float2 (512KB)
    // 32..36 : xw16 [2048][1024] fp16 (attn out / out-proj in)
    // 36..44 : W16 x4 slots (Wq,Wk,Wv,Wp)
    // 44..48 : qh  [B,H,512,64] fp16
    // 48..64 : kh  [B,H,2048,64] fp16
    // 64..80 : vt  [B,H,64,2048] fp16
    char* ws = (char*)d_ws;
    float2*   tab   = (float2*)  (ws);
    _Float16* xw16  = (_Float16*)(ws + (32u << 20));
    _Float16* W16   = (_Float16*)(ws + (36u << 20));
    _Float16* qhp   = (_Float16*)(ws + (44u << 20));
    _Float16* khp   = (_Float16*)(ws + (48u << 20));
    _Float16* vtp   = (_Float16*)(ws + (64u << 20));

    cvt_w_tab<<<4352, 256, 0, stream>>>(Wq, Wk, Wv, Wp, W16, tab);

    gemm_proj<<<1152, 256, 0, stream>>>(query, key, value, W16, qpos, kpos, tab,
                                        qhp, khp, vtp);

    attn_fused<<<256, 512, 0, stream>>>(qhp, khp, vtp, xw16);

    gemm_out<<<dim3(8, 16), 256, 0, stream>>>(xw16, W16 + (3u << 20), out, bp);
}

// Round 6
// 271.265 us; speedup vs baseline: 1.0103x; 1.0103x over previous
//
#include <hip/hip_runtime.h>
#include <math.h>

// Round 14: un-bundle round-13.  The fp32-A reg-staging was the regression
// (vmcnt(0)+cvt+ds_write serial chain at the top of every K-step: all pipes
// fell together, 56->106us).  Reverted to the proven round-12 structure
// (fp16 cvt pass + global_load_lds A/B staging, 0 conflicts, FETCH at the
// unique-bytes floor).  KEPT from round 13: RoPE fused into the projection
// epilogue (rope_qk stays deleted; table built in cvt_all's spare blocks,
// stored in d_out's first 512KB which is dead until gemm_out overwrites it).
// Launches: cvt_all, gemm_qkv(+rope), attn_fused, gemm_out.
#define B_ 4
#define NQ 512
#define NK 2048
#define C_ 1024
#define H_ 16
#define D_ 64
#define KK 1024

typedef __attribute__((ext_vector_type(8))) _Float16 half8;
typedef __attribute__((ext_vector_type(4))) _Float16 half4;
typedef __attribute__((ext_vector_type(4))) float float4v;

// async global->LDS, 16B per lane (wave-uniform LDS base + lane*16 by HW)
__device__ __forceinline__ void g2l16(const _Float16* g, _Float16* l)
{
    __builtin_amdgcn_global_load_lds(
        (const __attribute__((address_space(1))) unsigned int*)g,
        (__attribute__((address_space(3))) unsigned int*)l, 16, 0, 0);
}

// ---------------------------------------------------------------------------
// blocks 0..4095: W fp32->fp16.  blocks 4096..22527: q/k/v fp32->fp16.
// blocks 22528..22783: rope table tab[p*32+i] = (cos,sin)(p * 10000^(-i/32)).
// ---------------------------------------------------------------------------
__global__ __launch_bounds__(256) void cvt_all(const float* __restrict__ W0,
                                               const float* __restrict__ W1,
                                               const float* __restrict__ W2,
                                               const float* __restrict__ W3,
                                               const float* __restrict__ q,
                                               const float* __restrict__ k,
                                               const float* __restrict__ v,
                                               _Float16* __restrict__ W16,
                                               _Float16* __restrict__ xq,
                                               _Float16* __restrict__ xk,
                                               _Float16* __restrict__ xv,
                                               float2* __restrict__ tab)
{
    const int blk = blockIdx.x;
    if (blk >= 22528) {
        const int idx = (blk - 22528) * 256 + threadIdx.x;   // 0..65535
        const int p = idx >> 5, i = idx & 31;
        double f = 1.0;
        if (i & 1)  f *= 0.7498942093324559;    // 10^-0.125
        if (i & 2)  f *= 0.5623413251903491;    // 10^-0.25
        if (i & 4)  f *= 0.31622776601683794;   // 10^-0.5
        if (i & 8)  f *= 0.1;
        if (i & 16) f *= 0.01;
        const double ang = (double)p * f;
        const double TWO_PI = 6.2831853071795864769;
        const double INV_TWO_PI = 0.15915494309189533577;
        const float red = (float)(ang - TWO_PI * floor(ang * INV_TWO_PI));
        float s, c;
        sincosf(red, &s, &c);
        tab[idx] = make_float2(c, s);
        return;
    }
    const float* src; _Float16* dst; int row;
    if (blk < 4096) {
        const int w = blk >> 10; row = blk & 1023;
        src = (w == 0) ? W0 : (w == 1) ? W1 : (w == 2) ? W2 : W3;
        dst = W16 + ((size_t)w << 20);
    } else {
        const int b2 = blk - 4096;
        if (b2 < 2048)       { src = q; dst = xq; row = b2; }
        else if (b2 < 10240) { src = k; dst = xk; row = b2 - 2048; }
        else                 { src = v; dst = xv; row = b2 - 10240; }
    }
    const int col = threadIdx.x * 4;
    float4 f = *(const float4*)(src + (size_t)row * 1024 + col);
    half4 h;
    h[0] = (_Float16)f.x; h[1] = (_Float16)f.y;
    h[2] = (_Float16)f.z; h[3] = (_Float16)f.w;
    *(half4*)(dst + (size_t)row * 1024 + col) = h;
}

// ---------------------------------------------------------------------------
// Q/K/V projections with fused RoPE epilogue.  128x128 tile, BK=64, 4 waves,
// global_load_lds staging w/ XOR-octet swizzle (round-12 proven: 0 conflicts,
// FETCH at unique-bytes floor).  XCD-grouped linear grid of 1152.
// mode 0 (Q,K): rope + scatter [B,H,1<<nsh,64].  Pairs (i,i+32) of one head
// are fragments j and j+2 of the SAME lane (d = j*16+fm, head uniform/wave).
// mode 2 (V): transposed scatter [B,H,64,NK].
// ---------------------------------------------------------------------------
__global__ __launch_bounds__(256) void gemm_qkv(const _Float16* __restrict__ xq,
                                                const _Float16* __restrict__ xk,
                                                const _Float16* __restrict__ xv,
                                                const _Float16* __restrict__ W16,
                                                const int* __restrict__ qpos,
                                                const int* __restrict__ kpos,
                                                const float2* __restrict__ tab,
                                                _Float16* __restrict__ qhp,
                                                _Float16* __restrict__ khp,
                                                _Float16* __restrict__ vtp)
{
    __shared__ _Float16 sA[128 * 64];
    __shared__ _Float16 sB[128 * 64];

    const int lbid = blockIdx.x;            // 0..1151
    const int xcd = lbid & 7;
    const int seq = lbid >> 3;              // 0..143
    const int y = xcd + 8 * (seq >> 3);     // m-panel 0..143
    const int n0 = (seq & 7) * 128;

    const _Float16* A; const _Float16* Bw; _Float16* Yh; const int* pos;
    int nsh, m0, mode; float scale;
    if (y < 64)       { A = xk; Bw = W16 + (1u << 20); Yh = khp; pos = kpos;   nsh = 11; m0 = y * 128;         mode = 0; scale = 1.0f;   }
    else if (y < 128) { A = xv; Bw = W16 + (2u << 20); Yh = vtp; pos = nullptr; nsh = 11; m0 = (y - 64) * 128;  mode = 2; scale = 0.0f;   }
    else              { A = xq; Bw = W16;              Yh = qhp; pos = qpos;   nsh = 9;  m0 = (y - 128) * 128; mode = 0; scale = 0.125f; }

    const int tid = threadIdx.x;
    const int lane = tid & 63, wave = tid >> 6;
    const int wm = (wave >> 1) * 64, wn = (wave & 1) * 64;
    const int fm = lane & 15, quad = lane >> 4;

    const int srow = wave * 32 + (lane >> 3);
    const int soct = (lane & 7) ^ (srow & 7);
    const _Float16* gA = A  + (size_t)(m0 + srow) * KK + soct * 8;
    const _Float16* gB = Bw + (size_t)(n0 + srow) * KK + soct * 8;

    float4v acc[4][4];
    #pragma unroll
    for (int i = 0; i < 4; ++i)
        #pragma unroll
        for (int j = 0; j < 4; ++j)
            #pragma unroll
            for (int e = 0; e < 4; ++e) acc[i][j][e] = 0.0f;

    for (int k0 = 0; k0 < KK; k0 += 64) {
        __syncthreads();
        #pragma unroll
        for (int u = 0; u < 4; ++u) {
            g2l16(gA + (size_t)u * 8 * KK + k0, &sA[(wave * 32 + u * 8) * 64]);
            g2l16(gB + (size_t)u * 8 * KK + k0, &sB[(wave * 32 + u * 8) * 64]);
        }
        __syncthreads();

        #pragma unroll
        for (int ks = 0; ks < 2; ++ks) {
            const int po = ((ks * 4 + quad) ^ (fm & 7)) * 8;
            half8 a[4], b[4];
            #pragma unroll
            for (int i = 0; i < 4; ++i) {
                a[i] = *(const half8*)&sA[(wm + i * 16 + fm) * 64 + po];
                b[i] = *(const half8*)&sB[(wn + i * 16 + fm) * 64 + po];
            }
            __builtin_amdgcn_s_setprio(1);
            #pragma unroll
            for (int i = 0; i < 4; ++i)
                #pragma unroll
                for (int j = 0; j < 4; ++j)
                    acc[i][j] = __builtin_amdgcn_mfma_f32_16x16x32_f16(a[i], b[j], acc[i][j], 0, 0, 0);
            __builtin_amdgcn_s_setprio(0);
        }
    }

    const int rr = quad * 4;
    if (mode == 0) {
        // fused RoPE: within-head dim = j*16+fm; partners (i,i+32) = (j, j+2).
        const int nmask = (1 << nsh) - 1;
        const int hidx = (n0 + wn) >> 6;    // head, uniform per wave
        #pragma unroll
        for (int i = 0; i < 4; ++i)
            #pragma unroll
            for (int r = 0; r < 4; ++r) {
                const int m = m0 + wm + i * 16 + rr + r;
                const int b = m >> nsh, n = m & nmask;
                const int p = pos[(b << nsh) + n];
                const float2 cs0 = tab[p * 32 + fm];
                const float2 cs1 = tab[p * 32 + 16 + fm];
                const float x0 = acc[i][0][r], x2 = acc[i][2][r];
                const float x1 = acc[i][1][r], x3 = acc[i][3][r];
                const float o0 = (x0 * cs0.x - x2 * cs0.y) * scale;
                const float o2 = (x2 * cs0.x + x0 * cs0.y) * scale;
                const float o1 = (x1 * cs1.x - x3 * cs1.y) * scale;
                const float o3 = (x3 * cs1.x + x1 * cs1.y) * scale;
                const size_t base = ((((size_t)b * H_ + hidx) << nsh) + n) * 64 + fm;
                Yh[base +  0] = (_Float16)o0;
                Yh[base + 16] = (_Float16)o1;
                Yh[base + 32] = (_Float16)o2;
                Yh[base + 48] = (_Float16)o3;
            }
    } else {
        // V: transposed scatter [B,H,64,NK], no rope
        const int nmask = (1 << nsh) - 1;
        #pragma unroll
        for (int i = 0; i < 4; ++i)
            #pragma unroll
            for (int r = 0; r < 4; ++r) {
                const int m = m0 + wm + i * 16 + rr + r;
                const int b = m >> nsh, n = m & nmask;
                #pragma unroll
                for (int j = 0; j < 4; ++j) {
                    const int c = n0 + wn + j * 16 + fm;
                    Yh[(((size_t)(b * H_ + (c >> 6)) * 64) + (c & 63)) * NK + n] = (_Float16)acc[i][j][r];
                }
            }
    }
}

// ---------------------------------------------------------------------------
// Output projection (fp16 A/B via global_load_lds, fp32 out + bias).
// ---------------------------------------------------------------------------
__global__ __launch_bounds__(256) void gemm_out(const _Float16* __restrict__ A,
                                                const _Float16* __restrict__ Bw,
                                                float* __restrict__ Yf,
                                                const float* __restrict__ bias)
{
    __shared__ _Float16 sA[128 * 64];
    __shared__ _Float16 sB[128 * 64];

    const int tid = threadIdx.x;
    const int lane = tid & 63, wave = tid >> 6;
    const int n0 = blockIdx.x * 128, m0 = blockIdx.y * 128;
    const int wm = (wave >> 1) * 64, wn = (wave & 1) * 64;
    const int fm = lane & 15, quad = lane >> 4;

    const int srow = wave * 32 + (lane >> 3);
    const int soct = (lane & 7) ^ (srow & 7);
    const _Float16* gA = A  + (size_t)(m0 + srow) * KK + soct * 8;
    const _Float16* gB = Bw + (size_t)(n0 + srow) * KK + soct * 8;

    float4v acc[4][4];
    #pragma unroll
    for (int i = 0; i < 4; ++i)
        #pragma unroll
        for (int j = 0; j < 4; ++j)
            #pragma unroll
            for (int e = 0; e < 4; ++e) acc[i][j][e] = 0.0f;

    for (int k0 = 0; k0 < KK; k0 += 64) {
        __syncthreads();
        #pragma unroll
        for (int u = 0; u < 4; ++u) {
            g2l16(gA + (size_t)u * 8 * KK + k0, &sA[(wave * 32 + u * 8) * 64]);
            g2l16(gB + (size_t)u * 8 * KK + k0, &sB[(wave * 32 + u * 8) * 64]);
        }
        __syncthreads();

        #pragma unroll
        for (int ks = 0; ks < 2; ++ks) {
            const int po = ((ks * 4 + quad) ^ (fm & 7)) * 8;
            half8 a[4], b[4];
            #pragma unroll
            for (int i = 0; i < 4; ++i) {
                a[i] = *(const half8*)&sA[(wm + i * 16 + fm) * 64 + po];
                b[i] = *(const half8*)&sB[(wn + i * 16 + fm) * 64 + po];
            }
            __builtin_amdgcn_s_setprio(1);
            #pragma unroll
            for (int i = 0; i < 4; ++i)
                #pragma unroll
                for (int j = 0; j < 4; ++j)
                    acc[i][j] = __builtin_amdgcn_mfma_f32_16x16x32_f16(a[i], b[j], acc[i][j], 0, 0, 0);
            __builtin_amdgcn_s_setprio(0);
        }
    }

    const int rr = quad * 4;
    #pragma unroll
    for (int i = 0; i < 4; ++i)
        #pragma unroll
        for (int r = 0; r < 4; ++r) {
            const int m = m0 + wm + i * 16 + rr + r;
            #pragma unroll
            for (int j = 0; j < 4; ++j) {
                const int c = n0 + wn + j * 16 + fm;
                Yf[(size_t)m * 1024 + c] = acc[i][j][r] + bias[c];
            }
        }
}

// ---------------------------------------------------------------------------
// Fused flash attention (round 10, unchanged): LDS-shared K/V tiles,
// double-buffered global_load_lds staging, 8 waves each owning 16 queries.
// ---------------------------------------------------------------------------
__global__ __launch_bounds__(512) void attn_fused(const _Float16* __restrict__ qh,
                                                  const _Float16* __restrict__ kh,
                                                  const _Float16* __restrict__ vt,
                                                  _Float16* __restrict__ xw16)
{
    __shared__ _Float16 sK[2][64 * 64];
    __shared__ _Float16 sV[2][64 * 64];
    __shared__ _Float16 ps[8][16][66];

    const int tid = threadIdx.x;
    const int lane = tid & 63, wv = tid >> 6;   // 8 waves
    const int bhi = blockIdx.x & 63;            // XCD key
    const int qquad = blockIdx.x >> 6;          // 0..3
    const size_t bh = (size_t)bhi;
    const int qt = qquad * 8 + wv;              // q-tile 0..31 (16 queries)

    const int fm = lane & 15;
    const int quad = lane >> 4;
    const int fq = quad * 8;

    const _Float16* kb = kh + bh * NK * 64;
    const _Float16* vb = vt + bh * (size_t)64 * NK;

    const int r0 = lane >> 3;
    const int c4 = lane & 7;
    const int sch = c4 ^ r0;
    const _Float16* gK = kb + (size_t)(wv * 8 + r0) * 64 + sch * 8;
    const _Float16* gV = vb + (size_t)(wv * 8 + r0) * NK + sch * 8;

    const _Float16* qb = qh + (bh * NQ + (size_t)qt * 16) * 64;
    half8 aq[2];
    aq[0] = *(const half8*)(qb + (size_t)fm * 64 + fq);
    aq[1] = *(const half8*)(qb + (size_t)fm * 64 + 32 + fq);

    float l_acc[4] = {};
    float4v O[4];
    #pragma unroll
    for (int j = 0; j < 4; ++j)
        #pragma unroll
        for (int e = 0; e < 4; ++e) O[j][e] = 0.0f;

    const float4v z4 = {0.0f, 0.0f, 0.0f, 0.0f};

    g2l16(gK, &sK[0][wv * 512]);
    g2l16(gV, &sV[0][wv * 512]);
    __syncthreads();

    for (int it = 0; it < 32; ++it) {
        const int cur = it & 1;
        if (it < 31) {
            g2l16(gK + (size_t)(it + 1) * 64 * 64, &sK[cur ^ 1][wv * 512]);
            g2l16(gV + (it + 1) * 64,              &sV[cur ^ 1][wv * 512]);
        }
        const _Float16* Kc = sK[cur];
        const _Float16* Vc = sV[cur];

        half8 bk[4][2];
        #pragma unroll
        for (int j = 0; j < 4; ++j)
            #pragma unroll
            for (int ks = 0; ks < 2; ++ks)
                bk[j][ks] = *(const half8*)&Kc[(j * 16 + fm) * 64 + (((ks * 4 + quad) ^ (fm & 7)) * 8)];

        float4v s[4];
        __builtin_amdgcn_s_setprio(1);
        #pragma unroll
        for (int j = 0; j < 4; ++j) {
            s[j] = __builtin_amdgcn_mfma_f32_16x16x32_f16(aq[0], bk[j][0], z4, 0, 0, 0);
            s[j] = __builtin_amdgcn_mfma_f32_16x16x32_f16(aq[1], bk[j][1], s[j], 0, 0, 0);
        }
        __builtin_amdgcn_s_setprio(0);

        half8 bv[4][2];
        #pragma unroll
        for (int j = 0; j < 4; ++j)
            #pragma unroll
            for (int ks = 0; ks < 2; ++ks)
                bv[j][ks] = *(const half8*)&Vc[(j * 16 + fm) * 64 + (((ks * 4 + quad) ^ (fm & 7)) * 8)];

        #pragma unroll
        for (int j = 0; j < 4; ++j)
            #pragma unroll
            for (int r = 0; r < 4; ++r) {
                const float p = __expf(s[j][r]);
                l_acc[r] += p;
                ps[wv][quad * 4 + r][16 * j + fm] = (_Float16)p;
            }

        __builtin_amdgcn_s_setprio(1);
        #pragma unroll
        for (int ks = 0; ks < 2; ++ks) {
            half8 pa = *(const half8*)&ps[wv][fm][ks * 32 + fq];
            #pragma unroll
            for (int j = 0; j < 4; ++j)
                O[j] = __builtin_amdgcn_mfma_f32_16x16x32_f16(pa, bv[j][ks], O[j], 0, 0, 0);
        }
        __builtin_amdgcn_s_setprio(0);

        __syncthreads();
    }

    #pragma unroll
    for (int r = 0; r < 4; ++r) {
        float l = l_acc[r];
        l += __shfl_xor(l, 1);
        l += __shfl_xor(l, 2);
        l += __shfl_xor(l, 4);
        l += __shfl_xor(l, 8);
        const float inv = 1.0f / l;
        const int qr = quad * 4 + r;
        const int row = (bhi >> 4) * 512 + qt * 16 + qr;
        #pragma unroll
        for (int j = 0; j < 4; ++j) {
            const int col = (bhi & 15) * 64 + j * 16 + fm;
            xw16[(size_t)row * 1024 + col] = (_Float16)(O[j][r] * inv);
        }
    }
}

// ---------------------------------------------------------------------------
extern "C" void kernel_launch(void* const* d_in, const int* in_sizes, int n_in,
                              void* d_out, int out_size, void* d_ws, size_t ws_size,
                              hipStream_t stream)
{
    const float* query = (const float*)d_in[0];
    const float* key   = (const float*)d_in[1];
    const float* value = (const float*)d_in[2];
    const int*   qpos  = (const int*)d_in[3];
    const int*   kpos  = (const int*)d_in[4];
    const float* Wq    = (const float*)d_in[5];
    const float* Wk    = (const float*)d_in[6];
    const float* Wv    = (const float*)d_in[7];
    const float* Wp    = (const float*)d_in[8];
    const float* bp    = (const float*)d_in[9];
    float* out = (float*)d_out;

    // ws layout (MiB), 80 total:
    //  0..16 : xk16 [8192][1024] fp16 (free after gemm_qkv)
    // 16..32 : xv16 [8192][1024] fp16 (free after gemm_qkv)
    // 32..36 : xq16 [2048][1024] fp16 -> reused as xw16 (attn out)
    // 36..44 : W16 x4 slots (Wq,Wk,Wv,Wp)
    // 44..48 : qh  [B,H,512,64] fp16
    // 48..64 : kh  [B,H,2048,64] fp16
    // 64..80 : vt  [B,H,64,2048] fp16
    // rope table tab (512KB) lives in d_out (dead until gemm_out overwrites).
    char* ws = (char*)d_ws;
    _Float16* xk16  = (_Float16*)(ws);
    _Float16* xv16  = (_Float16*)(ws + (16u << 20));
    _Float16* xq16  = (_Float16*)(ws + (32u << 20));
    _Float16* W16   = (_Float16*)(ws + (36u << 20));
    _Float16* qhp   = (_Float16*)(ws + (44u << 20));
    _Float16* khp   = (_Float16*)(ws + (48u << 20));
    _Float16* vtp   = (_Float16*)(ws + (64u << 20));
    float2*   tab   = (float2*)d_out;            // scratch until gemm_out

    cvt_all<<<22784, 256, 0, stream>>>(Wq, Wk, Wv, Wp, query, key, value,
                                       W16, xq16, xk16, xv16, tab);

    gemm_qkv<<<1152, 256, 0, stream>>>(xq16, xk16, xv16, W16, qpos, kpos, tab,
                                       qhp, khp, vtp);

    attn_fused<<<256, 512, 0, stream>>>(qhp, khp, vtp, xq16);

    gemm_out<<<dim3(8, 16), 256, 0, stream>>>(xq16, W16 + (3u << 20), out, bp);
}

// Round 7
// 256.486 us; speedup vs baseline: 1.0685x; 1.0576x over previous
//
#include <hip/hip_runtime.h>
#include <math.h>

// Round 15: un-bundle the rope fusion (round-6 measured it at +32us inside
// gemm_qkv's epilogue vs ~28us of work absorbed: dependent pos->tab->store
// chain at 16% occupancy + codegen perturbation).
//  - gemm_qkv reverted to the EXACT round-4 structure (proven 56us,
//    MfmaUtil 27%, FETCH at floor, 0 bank conflicts).
//  - RoPE as a standalone TABLE-DRIVEN kernel: 2x half4 loads + 4x float2
//    table loads + 8 FMA per thread, pure HBM-bound (~42MB RT ~ 7-10us),
//    replacing round-4's f64-chain rope (~25us).
//  - cos/sin table still built in cvt_all's spare blocks, stored in d_out's
//    first 512KB (dead until gemm_out overwrites; proven in round 6).
// attn_fused, gemm_out unchanged.
#define B_ 4
#define NQ 512
#define NK 2048
#define C_ 1024
#define H_ 16
#define D_ 64
#define KK 1024

typedef __attribute__((ext_vector_type(8))) _Float16 half8;
typedef __attribute__((ext_vector_type(4))) _Float16 half4;
typedef __attribute__((ext_vector_type(4))) float float4v;

// async global->LDS, 16B per lane (wave-uniform LDS base + lane*16 by HW)
__device__ __forceinline__ void g2l16(const _Float16* g, _Float16* l)
{
    __builtin_amdgcn_global_load_lds(
        (const __attribute__((address_space(1))) unsigned int*)g,
        (__attribute__((address_space(3))) unsigned int*)l, 16, 0, 0);
}

// ---------------------------------------------------------------------------
// blocks 0..4095: W fp32->fp16.  blocks 4096..22527: q/k/v fp32->fp16.
// blocks 22528..22783: rope table tab[p*32+i] = (cos,sin)(p * 10000^(-i/32)).
// ---------------------------------------------------------------------------
__global__ __launch_bounds__(256) void cvt_all(const float* __restrict__ W0,
                                               const float* __restrict__ W1,
                                               const float* __restrict__ W2,
                                               const float* __restrict__ W3,
                                               const float* __restrict__ q,
                                               const float* __restrict__ k,
                                               const float* __restrict__ v,
                                               _Float16* __restrict__ W16,
                                               _Float16* __restrict__ xq,
                                               _Float16* __restrict__ xk,
                                               _Float16* __restrict__ xv,
                                               float2* __restrict__ tab)
{
    const int blk = blockIdx.x;
    if (blk >= 22528) {
        const int idx = (blk - 22528) * 256 + threadIdx.x;   // 0..65535
        const int p = idx >> 5, i = idx & 31;
        double f = 1.0;
        if (i & 1)  f *= 0.7498942093324559;    // 10^-0.125
        if (i & 2)  f *= 0.5623413251903491;    // 10^-0.25
        if (i & 4)  f *= 0.31622776601683794;   // 10^-0.5
        if (i & 8)  f *= 0.1;
        if (i & 16) f *= 0.01;
        const double ang = (double)p * f;
        const double TWO_PI = 6.2831853071795864769;
        const double INV_TWO_PI = 0.15915494309189533577;
        const float red = (float)(ang - TWO_PI * floor(ang * INV_TWO_PI));
        float s, c;
        sincosf(red, &s, &c);
        tab[idx] = make_float2(c, s);
        return;
    }
    const float* src; _Float16* dst; int row;
    if (blk < 4096) {
        const int w = blk >> 10; row = blk & 1023;
        src = (w == 0) ? W0 : (w == 1) ? W1 : (w == 2) ? W2 : W3;
        dst = W16 + ((size_t)w << 20);
    } else {
        const int b2 = blk - 4096;
        if (b2 < 2048)       { src = q; dst = xq; row = b2; }
        else if (b2 < 10240) { src = k; dst = xk; row = b2 - 2048; }
        else                 { src = v; dst = xv; row = b2 - 10240; }
    }
    const int col = threadIdx.x * 4;
    float4 f = *(const float4*)(src + (size_t)row * 1024 + col);
    half4 h;
    h[0] = (_Float16)f.x; h[1] = (_Float16)f.y;
    h[2] = (_Float16)f.z; h[3] = (_Float16)f.w;
    *(half4*)(dst + (size_t)row * 1024 + col) = h;
}

// ---------------------------------------------------------------------------
// 128x128 tile, BK=64, 4 waves, 4x4 16x16x32 MFMA; global_load_lds staging
// with XOR-octet swizzle (proven conflict-free).  Round-4 exact.
// mode 0: fp16 scatter [B,H,1<<nsh,64]; mode 1: fp32+bias row-major;
// mode 2: fp16 scatter transposed [B,H,64,NK].
// ---------------------------------------------------------------------------
__device__ __forceinline__ void gemm_body(const _Float16* __restrict__ A,
                                          const _Float16* __restrict__ Bw,
                                          _Float16* __restrict__ Yh,
                                          float* __restrict__ Yf,
                                          int mode, int nsh, int m0, int n0,
                                          const float* __restrict__ bias,
                                          _Float16* sA, _Float16* sB)
{
    const int tid = threadIdx.x;
    const int lane = tid & 63, wave = tid >> 6;
    const int wm = (wave >> 1) * 64, wn = (wave & 1) * 64;
    const int fm = lane & 15, quad = lane >> 4;

    const int srow = wave * 32 + (lane >> 3);
    const int soct = (lane & 7) ^ (srow & 7);
    const _Float16* gA = A  + (size_t)(m0 + srow) * KK + soct * 8;
    const _Float16* gB = Bw + (size_t)(n0 + srow) * KK + soct * 8;

    float4v acc[4][4];
    #pragma unroll
    for (int i = 0; i < 4; ++i)
        #pragma unroll
        for (int j = 0; j < 4; ++j)
            #pragma unroll
            for (int e = 0; e < 4; ++e) acc[i][j][e] = 0.0f;

    for (int k0 = 0; k0 < KK; k0 += 64) {
        __syncthreads();
        #pragma unroll
        for (int u = 0; u < 4; ++u) {
            g2l16(gA + (size_t)u * 8 * KK + k0, &sA[(wave * 32 + u * 8) * 64]);
            g2l16(gB + (size_t)u * 8 * KK + k0, &sB[(wave * 32 + u * 8) * 64]);
        }
        __syncthreads();

        #pragma unroll
        for (int ks = 0; ks < 2; ++ks) {
            const int po = ((ks * 4 + quad) ^ (fm & 7)) * 8;
            half8 a[4], b[4];
            #pragma unroll
            for (int i = 0; i < 4; ++i) {
                a[i] = *(const half8*)&sA[(wm + i * 16 + fm) * 64 + po];
                b[i] = *(const half8*)&sB[(wn + i * 16 + fm) * 64 + po];
            }
            __builtin_amdgcn_s_setprio(1);
            #pragma unroll
            for (int i = 0; i < 4; ++i)
                #pragma unroll
                for (int j = 0; j < 4; ++j)
                    acc[i][j] = __builtin_amdgcn_mfma_f32_16x16x32_f16(a[i], b[j], acc[i][j], 0, 0, 0);
            __builtin_amdgcn_s_setprio(0);
        }
    }

    const int rr = quad * 4;
    if (mode == 0) {
        const int nmask = (1 << nsh) - 1;
        #pragma unroll
        for (int i = 0; i < 4; ++i)
            #pragma unroll
            for (int r = 0; r < 4; ++r) {
                const int m = m0 + wm + i * 16 + rr + r;
                const int b = m >> nsh, n = m & nmask;
                #pragma unroll
                for (int j = 0; j < 4; ++j) {
                    const int c = n0 + wn + j * 16 + fm;
                    Yh[((((size_t)b * H_ + (c >> 6)) << nsh) + n) * 64 + (c & 63)] = (_Float16)acc[i][j][r];
                }
            }
    } else if (mode == 2) {
        const int nmask = (1 << nsh) - 1;
        #pragma unroll
        for (int i = 0; i < 4; ++i)
            #pragma unroll
            for (int r = 0; r < 4; ++r) {
                const int m = m0 + wm + i * 16 + rr + r;
                const int b = m >> nsh, n = m & nmask;
                #pragma unroll
                for (int j = 0; j < 4; ++j) {
                    const int c = n0 + wn + j * 16 + fm;
                    Yh[(((size_t)(b * H_ + (c >> 6)) * 64) + (c & 63)) * NK + n] = (_Float16)acc[i][j][r];
                }
            }
    } else {
        #pragma unroll
        for (int i = 0; i < 4; ++i)
            #pragma unroll
            for (int r = 0; r < 4; ++r) {
                const int m = m0 + wm + i * 16 + rr + r;
                #pragma unroll
                for (int j = 0; j < 4; ++j) {
                    const int c = n0 + wn + j * 16 + fm;
                    Yf[(size_t)m * 1024 + c] = acc[i][j][r] + bias[c];
                }
            }
    }
}

// Q/K/V projections, XCD-grouped linear grid of 1152 blocks (round-4 exact).
__global__ __launch_bounds__(256) void gemm_qkv(const _Float16* __restrict__ xq,
                                                const _Float16* __restrict__ xk,
                                                const _Float16* __restrict__ xv,
                                                const _Float16* __restrict__ W16,
                                                _Float16* __restrict__ qhp,
                                                _Float16* __restrict__ khp,
                                                _Float16* __restrict__ vtp)
{
    __shared__ _Float16 sA[128 * 64];
    __shared__ _Float16 sB[128 * 64];

    const int lbid = blockIdx.x;            // 0..1151
    const int xcd = lbid & 7;
    const int seq = lbid >> 3;              // 0..143
    const int y = xcd + 8 * (seq >> 3);     // m-panel 0..143
    const int n0 = (seq & 7) * 128;

    if (y < 64)
        gemm_body(xk, W16 + (1u << 20), khp, nullptr, 0, 11, y * 128, n0, nullptr, sA, sB);
    else if (y < 128)
        gemm_body(xv, W16 + (2u << 20), vtp, nullptr, 2, 11, (y - 64) * 128, n0, nullptr, sA, sB);
    else
        gemm_body(xq, W16, qhp, nullptr, 0, 9, (y - 128) * 128, n0, nullptr, sA, sB);
}

// Output projection (fp32 + bias).
__global__ __launch_bounds__(256) void gemm_out(const _Float16* __restrict__ A,
                                                const _Float16* __restrict__ Bw,
                                                float* __restrict__ Yf,
                                                const float* __restrict__ bias)
{
    __shared__ _Float16 sA[128 * 64];
    __shared__ _Float16 sB[128 * 64];
    gemm_body(A, Bw, nullptr, Yf, 1, 0, blockIdx.y * 128, blockIdx.x * 128, bias, sA, sB);
}

// ---------------------------------------------------------------------------
// Table-driven RoPE on qh and kh (in place).  One thread = 4 rotate-half
// pairs of one row: 2x half4 loads + 4x float2 tab loads + 8 FMA + 2x half4
// stores.  Pure HBM-bound.  q rows get scale 0.125 (D^-0.5).
// idx = row*8 + part; rows: 0..32767 = qh [B,H,512,64]; rest = kh [B,H,2048,64].
// ---------------------------------------------------------------------------
__global__ __launch_bounds__(256) void rope_tab(_Float16* __restrict__ qh,
                                                _Float16* __restrict__ kh,
                                                const int* __restrict__ qpos,
                                                const int* __restrict__ kpos,
                                                const float2* __restrict__ tab)
{
    const int idx = blockIdx.x * 256 + threadIdx.x;
    const int row = idx >> 3;
    const int d0 = (idx & 7) * 4;               // 0,4,...,28

    _Float16* ptr; int p; float scale;
    if (row < 32768) {                          // q: 4*16*512 rows
        ptr = qh + (size_t)row * 64;
        p = qpos[(row >> 13) * 512 + (row & 511)];
        scale = 0.125f;
    } else {                                    // k: 4*16*2048 rows
        const int rk = row - 32768;
        ptr = kh + (size_t)rk * 64;
        p = kpos[(rk >> 15) * 2048 + (rk & 2047)];
        scale = 1.0f;
    }

    half4 x1 = *(const half4*)(ptr + d0);
    half4 x2 = *(const half4*)(ptr + d0 + 32);
    const float2* tb = tab + p * 32 + d0;
    half4 o1, o2;
    #pragma unroll
    for (int u = 0; u < 4; ++u) {
        const float2 cs = tb[u];
        const float a = (float)x1[u], b = (float)x2[u];
        o1[u] = (_Float16)((a * cs.x - b * cs.y) * scale);
        o2[u] = (_Float16)((b * cs.x + a * cs.y) * scale);
    }
    *(half4*)(ptr + d0)      = o1;
    *(half4*)(ptr + d0 + 32) = o2;
}

// ---------------------------------------------------------------------------
// Fused flash attention (round 10, unchanged): LDS-shared K/V tiles,
// double-buffered global_load_lds staging, 8 waves each owning 16 queries.
// ---------------------------------------------------------------------------
__global__ __launch_bounds__(512) void attn_fused(const _Float16* __restrict__ qh,
                                                  const _Float16* __restrict__ kh,
                                                  const _Float16* __restrict__ vt,
                                                  _Float16* __restrict__ xw16)
{
    __shared__ _Float16 sK[2][64 * 64];
    __shared__ _Float16 sV[2][64 * 64];
    __shared__ _Float16 ps[8][16][66];

    const int tid = threadIdx.x;
    const int lane = tid & 63, wv = tid >> 6;   // 8 waves
    const int bhi = blockIdx.x & 63;            // XCD key
    const int qquad = blockIdx.x >> 6;          // 0..3
    const size_t bh = (size_t)bhi;
    const int qt = qquad * 8 + wv;              // q-tile 0..31 (16 queries)

    const int fm = lane & 15;
    const int quad = lane >> 4;
    const int fq = quad * 8;

    const _Float16* kb = kh + bh * NK * 64;
    const _Float16* vb = vt + bh * (size_t)64 * NK;

    const int r0 = lane >> 3;
    const int c4 = lane & 7;
    const int sch = c4 ^ r0;
    const _Float16* gK = kb + (size_t)(wv * 8 + r0) * 64 + sch * 8;
    const _Float16* gV = vb + (size_t)(wv * 8 + r0) * NK + sch * 8;

    const _Float16* qb = qh + (bh * NQ + (size_t)qt * 16) * 64;
    half8 aq[2];
    aq[0] = *(const half8*)(qb + (size_t)fm * 64 + fq);
    aq[1] = *(const half8*)(qb + (size_t)fm * 64 + 32 + fq);

    float l_acc[4] = {};
    float4v O[4];
    #pragma unroll
    for (int j = 0; j < 4; ++j)
        #pragma unroll
        for (int e = 0; e < 4; ++e) O[j][e] = 0.0f;

    const float4v z4 = {0.0f, 0.0f, 0.0f, 0.0f};

    g2l16(gK, &sK[0][wv * 512]);
    g2l16(gV, &sV[0][wv * 512]);
    __syncthreads();

    for (int it = 0; it < 32; ++it) {
        const int cur = it & 1;
        if (it < 31) {
            g2l16(gK + (size_t)(it + 1) * 64 * 64, &sK[cur ^ 1][wv * 512]);
            g2l16(gV + (it + 1) * 64,              &sV[cur ^ 1][wv * 512]);
        }
        const _Float16* Kc = sK[cur];
        const _Float16* Vc = sV[cur];

        half8 bk[4][2];
        #pragma unroll
        for (int j = 0; j < 4; ++j)
            #pragma unroll
            for (int ks = 0; ks < 2; ++ks)
                bk[j][ks] = *(const half8*)&Kc[(j * 16 + fm) * 64 + (((ks * 4 + quad) ^ (fm & 7)) * 8)];

        float4v s[4];
        __builtin_amdgcn_s_setprio(1);
        #pragma unroll
        for (int j = 0; j < 4; ++j) {
            s[j] = __builtin_amdgcn_mfma_f32_16x16x32_f16(aq[0], bk[j][0], z4, 0, 0, 0);
            s[j] = __builtin_amdgcn_mfma_f32_16x16x32_f16(aq[1], bk[j][1], s[j], 0, 0, 0);
        }
        __builtin_amdgcn_s_setprio(0);

        half8 bv[4][2];
        #pragma unroll
        for (int j = 0; j < 4; ++j)
            #pragma unroll
            for (int ks = 0; ks < 2; ++ks)
                bv[j][ks] = *(const half8*)&Vc[(j * 16 + fm) * 64 + (((ks * 4 + quad) ^ (fm & 7)) * 8)];

        #pragma unroll
        for (int j = 0; j < 4; ++j)
            #pragma unroll
            for (int r = 0; r < 4; ++r) {
                const float p = __expf(s[j][r]);
                l_acc[r] += p;
                ps[wv][quad * 4 + r][16 * j + fm] = (_Float16)p;
            }

        __builtin_amdgcn_s_setprio(1);
        #pragma unroll
        for (int ks = 0; ks < 2; ++ks) {
            half8 pa = *(const half8*)&ps[wv][fm][ks * 32 + fq];
            #pragma unroll
            for (int j = 0; j < 4; ++j)
                O[j] = __builtin_amdgcn_mfma_f32_16x16x32_f16(pa, bv[j][ks], O[j], 0, 0, 0);
        }
        __builtin_amdgcn_s_setprio(0);

        __syncthreads();
    }

    #pragma unroll
    for (int r = 0; r < 4; ++r) {
        float l = l_acc[r];
        l += __shfl_xor(l, 1);
        l += __shfl_xor(l, 2);
        l += __shfl_xor(l, 4);
        l += __shfl_xor(l, 8);
        const float inv = 1.0f / l;
        const int qr = quad * 4 + r;
        const int row = (bhi >> 4) * 512 + qt * 16 + qr;
        #pragma unroll
        for (int j = 0; j < 4; ++j) {
            const int col = (bhi & 15) * 64 + j * 16 + fm;
            xw16[(size_t)row * 1024 + col] = (_Float16)(O[j][r] * inv);
        }
    }
}

// ---------------------------------------------------------------------------
extern "C" void kernel_launch(void* const* d_in, const int* in_sizes, int n_in,
                              void* d_out, int out_size, void* d_ws, size_t ws_size,
                              hipStream_t stream)
{
    const float* query = (const float*)d_in[0];
    const float* key   = (const float*)d_in[1];
    const float* value = (const float*)d_in[2];
    const int*   qpos  = (const int*)d_in[3];
    const int*   kpos  = (const int*)d_in[4];
    const float* Wq    = (const float*)d_in[5];
    const float* Wk    = (const float*)d_in[6];
    const float* Wv    = (const float*)d_in[7];
    const float* Wp    = (const float*)d_in[8];
    const float* bp    = (const float*)d_in[9];
    float* out = (float*)d_out;

    // ws layout (MiB), 80 total:
    //  0..16 : xk16 [8192][1024] fp16 (free after gemm_qkv)
    // 16..32 : xv16 [8192][1024] fp16 (free after gemm_qkv)
    // 32..36 : xq16 [2048][1024] fp16 -> reused as xw16 (attn out)
    // 36..44 : W16 x4 slots (Wq,Wk,Wv,Wp)
    // 44..48 : qh  [B,H,512,64] fp16
    // 48..64 : kh  [B,H,2048,64] fp16
    // 64..80 : vt  [B,H,64,2048] fp16
    // rope table tab (512KB) lives in d_out (dead until gemm_out overwrites).
    char* ws = (char*)d_ws;
    _Float16* xk16  = (_Float16*)(ws);
    _Float16* xv16  = (_Float16*)(ws + (16u << 20));
    _Float16* xq16  = (_Float16*)(ws + (32u << 20));
    _Float16* W16   = (_Float16*)(ws + (36u << 20));
    _Float16* qhp   = (_Float16*)(ws + (44u << 20));
    _Float16* khp   = (_Float16*)(ws + (48u << 20));
    _Float16* vtp   = (_Float16*)(ws + (64u << 20));
    float2*   tab   = (float2*)d_out;            // scratch until gemm_out

    cvt_all<<<22784, 256, 0, stream>>>(Wq, Wk, Wv, Wp, query, key, value,
                                       W16, xq16, xk16, xv16, tab);

    gemm_qkv<<<1152, 256, 0, stream>>>(xq16, xk16, xv16, W16, qhp, khp, vtp);

    // (32768 + 131072) rows * 8 threads / 256 = 5120 blocks
    rope_tab<<<5120, 256, 0, stream>>>(qhp, khp, qpos, kpos, tab);

    attn_fused<<<256, 512, 0, stream>>>(qhp, khp, vtp, xq16);

    gemm_out<<<dim3(8, 16), 256, 0, stream>>>(xq16, W16 + (3u << 20), out, bp);
}

// Round 8
// 244.957 us; speedup vs baseline: 1.1188x; 1.0471x over previous
//
#include <hip/hip_runtime.h>
#include <math.h>

// Round 16: attention latency fix.  Budget analysis: attn ~50us (tied w/ gemm)
// at 344TF vs 7us MFMA floor; 1 block/CU + syncthreads-drained staging =
// latency-bound.  Changes (attn only, rest byte-identical to round 15):
//  - 4 waves/block, grid 512 (8 q-blocks per bh, same XCD L2 mapping) ->
//    2 independent blocks/CU: one computes while the other barriers.
//  - K/V triple-buffered, depth-2 prefetch, counted s_waitcnt vmcnt(8/4/0)
//    (round-11 gemm's proven loop skeleton): staging loads stay in flight
//    across barriers; trailing lgkmcnt(0)+s_barrier guards buffer reuse.
#define B_ 4
#define NQ 512
#define NK 2048
#define C_ 1024
#define H_ 16
#define D_ 64
#define KK 1024

typedef __attribute__((ext_vector_type(8))) _Float16 half8;
typedef __attribute__((ext_vector_type(4))) _Float16 half4;
typedef __attribute__((ext_vector_type(4))) float float4v;

// async global->LDS, 16B per lane (wave-uniform LDS base + lane*16 by HW)
__device__ __forceinline__ void g2l16(const _Float16* g, _Float16* l)
{
    __builtin_amdgcn_global_load_lds(
        (const __attribute__((address_space(1))) unsigned int*)g,
        (__attribute__((address_space(3))) unsigned int*)l, 16, 0, 0);
}

// ---------------------------------------------------------------------------
// blocks 0..4095: W fp32->fp16.  blocks 4096..22527: q/k/v fp32->fp16.
// blocks 22528..22783: rope table tab[p*32+i] = (cos,sin)(p * 10000^(-i/32)).
// ---------------------------------------------------------------------------
__global__ __launch_bounds__(256) void cvt_all(const float* __restrict__ W0,
                                               const float* __restrict__ W1,
                                               const float* __restrict__ W2,
                                               const float* __restrict__ W3,
                                               const float* __restrict__ q,
                                               const float* __restrict__ k,
                                               const float* __restrict__ v,
                                               _Float16* __restrict__ W16,
                                               _Float16* __restrict__ xq,
                                               _Float16* __restrict__ xk,
                                               _Float16* __restrict__ xv,
                                               float2* __restrict__ tab)
{
    const int blk = blockIdx.x;
    if (blk >= 22528) {
        const int idx = (blk - 22528) * 256 + threadIdx.x;   // 0..65535
        const int p = idx >> 5, i = idx & 31;
        double f = 1.0;
        if (i & 1)  f *= 0.7498942093324559;    // 10^-0.125
        if (i & 2)  f *= 0.5623413251903491;    // 10^-0.25
        if (i & 4)  f *= 0.31622776601683794;   // 10^-0.5
        if (i & 8)  f *= 0.1;
        if (i & 16) f *= 0.01;
        const double ang = (double)p * f;
        const double TWO_PI = 6.2831853071795864769;
        const double INV_TWO_PI = 0.15915494309189533577;
        const float red = (float)(ang - TWO_PI * floor(ang * INV_TWO_PI));
        float s, c;
        sincosf(red, &s, &c);
        tab[idx] = make_float2(c, s);
        return;
    }
    const float* src; _Float16* dst; int row;
    if (blk < 4096) {
        const int w = blk >> 10; row = blk & 1023;
        src = (w == 0) ? W0 : (w == 1) ? W1 : (w == 2) ? W2 : W3;
        dst = W16 + ((size_t)w << 20);
    } else {
        const int b2 = blk - 4096;
        if (b2 < 2048)       { src = q; dst = xq; row = b2; }
        else if (b2 < 10240) { src = k; dst = xk; row = b2 - 2048; }
        else                 { src = v; dst = xv; row = b2 - 10240; }
    }
    const int col = threadIdx.x * 4;
    float4 f = *(const float4*)(src + (size_t)row * 1024 + col);
    half4 h;
    h[0] = (_Float16)f.x; h[1] = (_Float16)f.y;
    h[2] = (_Float16)f.z; h[3] = (_Float16)f.w;
    *(half4*)(dst + (size_t)row * 1024 + col) = h;
}

// ---------------------------------------------------------------------------
// 128x128 tile, BK=64, 4 waves, 4x4 16x16x32 MFMA; global_load_lds staging
// with XOR-octet swizzle (proven conflict-free).  Round-4 exact.
// mode 0: fp16 scatter [B,H,1<<nsh,64]; mode 1: fp32+bias row-major;
// mode 2: fp16 scatter transposed [B,H,64,NK].
// ---------------------------------------------------------------------------
__device__ __forceinline__ void gemm_body(const _Float16* __restrict__ A,
                                          const _Float16* __restrict__ Bw,
                                          _Float16* __restrict__ Yh,
                                          float* __restrict__ Yf,
                                          int mode, int nsh, int m0, int n0,
                                          const float* __restrict__ bias,
                                          _Float16* sA, _Float16* sB)
{
    const int tid = threadIdx.x;
    const int lane = tid & 63, wave = tid >> 6;
    const int wm = (wave >> 1) * 64, wn = (wave & 1) * 64;
    const int fm = lane & 15, quad = lane >> 4;

    const int srow = wave * 32 + (lane >> 3);
    const int soct = (lane & 7) ^ (srow & 7);
    const _Float16* gA = A  + (size_t)(m0 + srow) * KK + soct * 8;
    const _Float16* gB = Bw + (size_t)(n0 + srow) * KK + soct * 8;

    float4v acc[4][4];
    #pragma unroll
    for (int i = 0; i < 4; ++i)
        #pragma unroll
        for (int j = 0; j < 4; ++j)
            #pragma unroll
            for (int e = 0; e < 4; ++e) acc[i][j][e] = 0.0f;

    for (int k0 = 0; k0 < KK; k0 += 64) {
        __syncthreads();
        #pragma unroll
        for (int u = 0; u < 4; ++u) {
            g2l16(gA + (size_t)u * 8 * KK + k0, &sA[(wave * 32 + u * 8) * 64]);
            g2l16(gB + (size_t)u * 8 * KK + k0, &sB[(wave * 32 + u * 8) * 64]);
        }
        __syncthreads();

        #pragma unroll
        for (int ks = 0; ks < 2; ++ks) {
            const int po = ((ks * 4 + quad) ^ (fm & 7)) * 8;
            half8 a[4], b[4];
            #pragma unroll
            for (int i = 0; i < 4; ++i) {
                a[i] = *(const half8*)&sA[(wm + i * 16 + fm) * 64 + po];
                b[i] = *(const half8*)&sB[(wn + i * 16 + fm) * 64 + po];
            }
            __builtin_amdgcn_s_setprio(1);
            #pragma unroll
            for (int i = 0; i < 4; ++i)
                #pragma unroll
                for (int j = 0; j < 4; ++j)
                    acc[i][j] = __builtin_amdgcn_mfma_f32_16x16x32_f16(a[i], b[j], acc[i][j], 0, 0, 0);
            __builtin_amdgcn_s_setprio(0);
        }
    }

    const int rr = quad * 4;
    if (mode == 0) {
        const int nmask = (1 << nsh) - 1;
        #pragma unroll
        for (int i = 0; i < 4; ++i)
            #pragma unroll
            for (int r = 0; r < 4; ++r) {
                const int m = m0 + wm + i * 16 + rr + r;
                const int b = m >> nsh, n = m & nmask;
                #pragma unroll
                for (int j = 0; j < 4; ++j) {
                    const int c = n0 + wn + j * 16 + fm;
                    Yh[((((size_t)b * H_ + (c >> 6)) << nsh) + n) * 64 + (c & 63)] = (_Float16)acc[i][j][r];
                }
            }
    } else if (mode == 2) {
        const int nmask = (1 << nsh) - 1;
        #pragma unroll
        for (int i = 0; i < 4; ++i)
            #pragma unroll
            for (int r = 0; r < 4; ++r) {
                const int m = m0 + wm + i * 16 + rr + r;
                const int b = m >> nsh, n = m & nmask;
                #pragma unroll
                for (int j = 0; j < 4; ++j) {
                    const int c = n0 + wn + j * 16 + fm;
                    Yh[(((size_t)(b * H_ + (c >> 6)) * 64) + (c & 63)) * NK + n] = (_Float16)acc[i][j][r];
                }
            }
    } else {
        #pragma unroll
        for (int i = 0; i < 4; ++i)
            #pragma unroll
            for (int r = 0; r < 4; ++r) {
                const int m = m0 + wm + i * 16 + rr + r;
                #pragma unroll
                for (int j = 0; j < 4; ++j) {
                    const int c = n0 + wn + j * 16 + fm;
                    Yf[(size_t)m * 1024 + c] = acc[i][j][r] + bias[c];
                }
            }
    }
}

// Q/K/V projections, XCD-grouped linear grid of 1152 blocks (round-4 exact).
__global__ __launch_bounds__(256) void gemm_qkv(const _Float16* __restrict__ xq,
                                                const _Float16* __restrict__ xk,
                                                const _Float16* __restrict__ xv,
                                                const _Float16* __restrict__ W16,
                                                _Float16* __restrict__ qhp,
                                                _Float16* __restrict__ khp,
                                                _Float16* __restrict__ vtp)
{
    __shared__ _Float16 sA[128 * 64];
    __shared__ _Float16 sB[128 * 64];

    const int lbid = blockIdx.x;            // 0..1151
    const int xcd = lbid & 7;
    const int seq = lbid >> 3;              // 0..143
    const int y = xcd + 8 * (seq >> 3);     // m-panel 0..143
    const int n0 = (seq & 7) * 128;

    if (y < 64)
        gemm_body(xk, W16 + (1u << 20), khp, nullptr, 0, 11, y * 128, n0, nullptr, sA, sB);
    else if (y < 128)
        gemm_body(xv, W16 + (2u << 20), vtp, nullptr, 2, 11, (y - 64) * 128, n0, nullptr, sA, sB);
    else
        gemm_body(xq, W16, qhp, nullptr, 0, 9, (y - 128) * 128, n0, nullptr, sA, sB);
}

// Output projection (fp32 + bias).
__global__ __launch_bounds__(256) void gemm_out(const _Float16* __restrict__ A,
                                                const _Float16* __restrict__ Bw,
                                                float* __restrict__ Yf,
                                                const float* __restrict__ bias)
{
    __shared__ _Float16 sA[128 * 64];
    __shared__ _Float16 sB[128 * 64];
    gemm_body(A, Bw, nullptr, Yf, 1, 0, blockIdx.y * 128, blockIdx.x * 128, bias, sA, sB);
}

// ---------------------------------------------------------------------------
// Table-driven RoPE on qh and kh (in place).  One thread = 4 rotate-half
// pairs of one row.  Pure HBM-bound.  q rows get scale 0.125 (D^-0.5).
// ---------------------------------------------------------------------------
__global__ __launch_bounds__(256) void rope_tab(_Float16* __restrict__ qh,
                                                _Float16* __restrict__ kh,
                                                const int* __restrict__ qpos,
                                                const int* __restrict__ kpos,
                                                const float2* __restrict__ tab)
{
    const int idx = blockIdx.x * 256 + threadIdx.x;
    const int row = idx >> 3;
    const int d0 = (idx & 7) * 4;               // 0,4,...,28

    _Float16* ptr; int p; float scale;
    if (row < 32768) {                          // q: 4*16*512 rows
        ptr = qh + (size_t)row * 64;
        p = qpos[(row >> 13) * 512 + (row & 511)];
        scale = 0.125f;
    } else {                                    // k: 4*16*2048 rows
        const int rk = row - 32768;
        ptr = kh + (size_t)rk * 64;
        p = kpos[(rk >> 15) * 2048 + (rk & 2047)];
        scale = 1.0f;
    }

    half4 x1 = *(const half4*)(ptr + d0);
    half4 x2 = *(const half4*)(ptr + d0 + 32);
    const float2* tb = tab + p * 32 + d0;
    half4 o1, o2;
    #pragma unroll
    for (int u = 0; u < 4; ++u) {
        const float2 cs = tb[u];
        const float a = (float)x1[u], b = (float)x2[u];
        o1[u] = (_Float16)((a * cs.x - b * cs.y) * scale);
        o2[u] = (_Float16)((b * cs.x + a * cs.y) * scale);
    }
    *(half4*)(ptr + d0)      = o1;
    *(half4*)(ptr + d0 + 32) = o2;
}

// ---------------------------------------------------------------------------
// Fused flash attention, latency-tolerant version.
// Grid 512 = qoct(8) x bh(64); bh = blk&63 -> XCD = blk%8 (L2 mapping kept).
// 4 waves/block (256 thr), wave wv owns q-tile qoct*4+wv (16 queries).
// K/V 64-key tiles triple-buffered in LDS, depth-2 prefetch with counted
// vmcnt (8/4/0) -- loads stay in flight across barriers (round-11 skeleton).
// Per iter: STAGE(t+2) | vmcnt(8) | bar | compute(t) | lgkm(0) | bar.
// LDS 56.25KB -> 2 blocks/CU resident.
// ---------------------------------------------------------------------------
__global__ __launch_bounds__(256) void attn_fused(const _Float16* __restrict__ qh,
                                                  const _Float16* __restrict__ kh,
                                                  const _Float16* __restrict__ vt,
                                                  _Float16* __restrict__ xw16)
{
    __shared__ _Float16 sK[3][64 * 64];
    __shared__ _Float16 sV[3][64 * 64];
    __shared__ _Float16 ps[4][16][66];

    const int tid = threadIdx.x;
    const int lane = tid & 63, wv = tid >> 6;   // 4 waves
    const int bhi = blockIdx.x & 63;            // XCD key
    const int qoct = blockIdx.x >> 6;           // 0..7
    const size_t bh = (size_t)bhi;
    const int qt = qoct * 4 + wv;               // q-tile 0..31 (16 queries)

    const int fm = lane & 15;
    const int quad = lane >> 4;
    const int fq = quad * 8;

    const _Float16* kb = kh + bh * NK * 64;
    const _Float16* vb = vt + bh * (size_t)64 * NK;

    // staging: wave wv covers tile rows wv*16 + u*8 + r0, u=0,1
    const int r0 = lane >> 3;
    const int c4 = lane & 7;
    const int sch = c4 ^ r0;
    const _Float16* gK = kb + (size_t)(wv * 16 + r0) * 64 + sch * 8;
    const _Float16* gV = vb + (size_t)(wv * 16 + r0) * NK + sch * 8;

#define STAGE(bf, t) do {                                                     \
        g2l16(gK + (size_t)(t) * 4096,        &sK[bf][(wv * 16) * 64]);       \
        g2l16(gK + (size_t)(t) * 4096 + 512,  &sK[bf][(wv * 16 + 8) * 64]);   \
        g2l16(gV + (t) * 64,                  &sV[bf][(wv * 16) * 64]);       \
        g2l16(gV + (size_t)8 * NK + (t) * 64, &sV[bf][(wv * 16 + 8) * 64]);   \
    } while (0)

    const _Float16* qb = qh + (bh * NQ + (size_t)qt * 16) * 64;
    half8 aq[2];
    aq[0] = *(const half8*)(qb + (size_t)fm * 64 + fq);
    aq[1] = *(const half8*)(qb + (size_t)fm * 64 + 32 + fq);

    float l_acc[4] = {};
    float4v O[4];
    #pragma unroll
    for (int j = 0; j < 4; ++j)
        #pragma unroll
        for (int e = 0; e < 4; ++e) O[j][e] = 0.0f;

    const float4v z4 = {0.0f, 0.0f, 0.0f, 0.0f};

    STAGE(0, 0);
    STAGE(1, 1);

    for (int it = 0; it < 32; ++it) {
        const int cur = it % 3;
        if (it + 2 < 32)
            STAGE((it + 2) % 3, it + 2);

        // counted wait: stage(it) retired; deeper prefetches stay in flight.
        if (it < 30)       asm volatile("s_waitcnt vmcnt(8)" ::: "memory");
        else if (it == 30) asm volatile("s_waitcnt vmcnt(4)" ::: "memory");
        else               asm volatile("s_waitcnt vmcnt(0)" ::: "memory");
        __builtin_amdgcn_sched_barrier(0);
        __builtin_amdgcn_s_barrier();           // tile it visible to all waves
        __builtin_amdgcn_sched_barrier(0);

        const _Float16* Kc = sK[cur];
        const _Float16* Vc = sV[cur];

        half8 bk[4][2];
        #pragma unroll
        for (int j = 0; j < 4; ++j)
            #pragma unroll
            for (int ks = 0; ks < 2; ++ks)
                bk[j][ks] = *(const half8*)&Kc[(j * 16 + fm) * 64 + (((ks * 4 + quad) ^ (fm & 7)) * 8)];

        float4v s[4];
        __builtin_amdgcn_s_setprio(1);
        #pragma unroll
        for (int j = 0; j < 4; ++j) {
            s[j] = __builtin_amdgcn_mfma_f32_16x16x32_f16(aq[0], bk[j][0], z4, 0, 0, 0);
            s[j] = __builtin_amdgcn_mfma_f32_16x16x32_f16(aq[1], bk[j][1], s[j], 0, 0, 0);
        }
        __builtin_amdgcn_s_setprio(0);

        half8 bv[4][2];
        #pragma unroll
        for (int j = 0; j < 4; ++j)
            #pragma unroll
            for (int ks = 0; ks < 2; ++ks)
                bv[j][ks] = *(const half8*)&Vc[(j * 16 + fm) * 64 + (((ks * 4 + quad) ^ (fm & 7)) * 8)];

        // P = exp(s) (scores pre-scaled by 0.125 in rope; fixed max 0 safe)
        #pragma unroll
        for (int j = 0; j < 4; ++j)
            #pragma unroll
            for (int r = 0; r < 4; ++r) {
                const float p = __expf(s[j][r]);
                l_acc[r] += p;
                ps[wv][quad * 4 + r][16 * j + fm] = (_Float16)p;
            }

        __builtin_amdgcn_s_setprio(1);
        #pragma unroll
        for (int ks = 0; ks < 2; ++ks) {
            half8 pa = *(const half8*)&ps[wv][fm][ks * 32 + fq];
            #pragma unroll
            for (int j = 0; j < 4; ++j)
                O[j] = __builtin_amdgcn_mfma_f32_16x16x32_f16(pa, bv[j][ks], O[j], 0, 0, 0);
        }
        __builtin_amdgcn_s_setprio(0);

        // all LDS reads of buf cur retired before any wave re-stages into it
        asm volatile("s_waitcnt lgkmcnt(0)" ::: "memory");
        __builtin_amdgcn_sched_barrier(0);
        __builtin_amdgcn_s_barrier();
        __builtin_amdgcn_sched_barrier(0);
    }
#undef STAGE

    // Epilogue: this wave exclusively owns its 16 queries -> direct write.
    #pragma unroll
    for (int r = 0; r < 4; ++r) {
        float l = l_acc[r];
        l += __shfl_xor(l, 1);
        l += __shfl_xor(l, 2);
        l += __shfl_xor(l, 4);
        l += __shfl_xor(l, 8);
        const float inv = 1.0f / l;
        const int qr = quad * 4 + r;
        const int row = (bhi >> 4) * 512 + qt * 16 + qr;
        #pragma unroll
        for (int j = 0; j < 4; ++j) {
            const int col = (bhi & 15) * 64 + j * 16 + fm;
            xw16[(size_t)row * 1024 + col] = (_Float16)(O[j][r] * inv);
        }
    }
}

// ---------------------------------------------------------------------------
extern "C" void kernel_launch(void* const* d_in, const int* in_sizes, int n_in,
                              void* d_out, int out_size, void* d_ws, size_t ws_size,
                              hipStream_t stream)
{
    const float* query = (const float*)d_in[0];
    const float* key   = (const float*)d_in[1];
    const float* value = (const float*)d_in[2];
    const int*   qpos  = (const int*)d_in[3];
    const int*   kpos  = (const int*)d_in[4];
    const float* Wq    = (const float*)d_in[5];
    const float* Wk    = (const float*)d_in[6];
    const float* Wv    = (const float*)d_in[7];
    const float* Wp    = (const float*)d_in[8];
    const float* bp    = (const float*)d_in[9];
    float* out = (float*)d_out;

    // ws layout (MiB), 80 total:
    //  0..16 : xk16 [8192][1024] fp16 (free after gemm_qkv)
    // 16..32 : xv16 [8192][1024] fp16 (free after gemm_qkv)
    // 32..36 : xq16 [2048][1024] fp16 -> reused as xw16 (attn out)
    // 36..44 : W16 x4 slots (Wq,Wk,Wv,Wp)
    // 44..48 : qh  [B,H,512,64] fp16
    // 48..64 : kh  [B,H,2048,64] fp16
    // 64..80 : vt  [B,H,64,2048] fp16
    // rope table tab (512KB) lives in d_out (dead until gemm_out overwrites).
    char* ws = (char*)d_ws;
    _Float16* xk16  = (_Float16*)(ws);
    _Float16* xv16  = (_Float16*)(ws + (16u << 20));
    _Float16* xq16  = (_Float16*)(ws + (32u << 20));
    _Float16* W16   = (_Float16*)(ws + (36u << 20));
    _Float16* qhp   = (_Float16*)(ws + (44u << 20));
    _Float16* khp   = (_Float16*)(ws + (48u << 20));
    _Float16* vtp   = (_Float16*)(ws + (64u << 20));
    float2*   tab   = (float2*)d_out;            // scratch until gemm_out

    cvt_all<<<22784, 256, 0, stream>>>(Wq, Wk, Wv, Wp, query, key, value,
                                       W16, xq16, xk16, xv16, tab);

    gemm_qkv<<<1152, 256, 0, stream>>>(xq16, xk16, xv16, W16, qhp, khp, vtp);

    rope_tab<<<5120, 256, 0, stream>>>(qhp, khp, qpos, kpos, tab);

    attn_fused<<<512, 256, 0, stream>>>(qhp, khp, vtp, xq16);

    gemm_out<<<dim3(8, 16), 256, 0, stream>>>(xq16, W16 + (3u << 20), out, bp);
}